// Round 14
// baseline (139.101 us; speedup 1.0000x reference)
//
#include <hip/hip_runtime.h>
#include <hip/hip_bf16.h>

typedef __attribute__((ext_vector_type(4))) unsigned int uint4v;
typedef __attribute__((ext_vector_type(8))) short short8;
typedef __attribute__((ext_vector_type(16))) float floatx16;

#define NROW 148
#define ROWB (20*512)                    // 10240 B per pad row (20 chunk-cols x 32ch x 16B)
#define BB   ((size_t)NROW*ROWB)         // per-batch bytes (1.51 MB)
#define COPYB ((size_t)8*BB)             // 12,124,160 per parity copy
#define STATS_OFF ((size_t)2*COPYB)      // 24,248,320
#define LDS_A_ROWS 38
#define ABUF (LDS_A_ROWS*2048)           // 77824
#define LDS_BYTES (2*ABUF)               // 155648 (A double-buffered via DMA)

__device__ __forceinline__ unsigned short f2b(float f){
  unsigned int u = __float_as_uint(f);
  return (unsigned short)((u + 0x7fffu + ((u >> 16) & 1u)) >> 16);  // RNE
}

__device__ __forceinline__ void gload_lds4(const void* g, void* l){
  __builtin_amdgcn_global_load_lds((const __attribute__((address_space(1))) unsigned int*)g,
                                   (__attribute__((address_space(3))) unsigned int*)l, 4, 0, 0);
}

// ---------------- Kernel 1: per-(b,c) mean/scale ----------------
__global__ __launch_bounds__(256) void k_stat(const float* __restrict__ x,
                                              float* __restrict__ stats){
  int bid = blockIdx.x;                  // = b*32 + c
  int t = threadIdx.x;
  const float* xc = x + ((size_t)bid << 14);
  float s = 0.f, ss = 0.f;
  #pragma unroll 4
  for (int k = 0; k < 64; ++k){
    float v = xc[t + (k << 8)];
    s += v; ss += v*v;
  }
  #pragma unroll
  for (int m = 32; m >= 1; m >>= 1){
    s  += __shfl_xor(s, m);
    ss += __shfl_xor(ss, m);
  }
  __shared__ float rs[4], rss[4];
  int wv = t >> 6, l = t & 63;
  if (l == 0){ rs[wv] = s; rss[wv] = ss; }
  __syncthreads();
  if (t == 0){
    float S  = rs[0]+rs[1]+rs[2]+rs[3];
    float SS = rss[0]+rss[1]+rss[2]+rss[3];
    float mean = S * (1.f/16384.f);
    float var  = (SS - S*mean) * (1.f/16383.f);   // ddof=1
    float sd = sqrtf(fmaxf(var, 0.f));
    stats[bid*2]   = mean;
    stats[bid*2+1] = (sd < 1e-9f) ? 0.f : 1.f/(sd*128.f);  // 1/(std*sqrt(16384))
  }
}

// ---------------- Kernel 2: standardize + 2 parity copies, chunk-interleaved ----------------
// copy p, chunk (b, r, col, ch), elements e=0..7:  xs_std[b][ch][(r-10)%128][(8*col+e+p)%128]
__global__ __launch_bounds__(512) void k_pack(const float* __restrict__ x,
                                              const float* __restrict__ stats,
                                              unsigned char* __restrict__ pad){
  __shared__ float rowbuf[32*129];       // +1 f32 pad per channel row -> conflict-free
  int bid = blockIdx.x;
  int b = bid & 7, rg = bid >> 3;        // rg 0..36, rows 4rg..4rg+3
  int t = threadIdx.x;
  int ch = t >> 4, xq = t & 15;
  float mean  = stats[(b*32 + ch)*2];
  float scale = stats[(b*32 + ch)*2 + 1];
  const float* xc = x + ((size_t)(b*32 + ch) << 14);
  for (int rr = 0; rr < 4; ++rr){
    int r = rg*4 + rr;
    int sy = (r + 118) & 127;            // (r-10) mod 128
    const float* src = xc + (sy << 7) + (xq << 3);
    float4 v0 = *(const float4*)src;
    float4 v1 = *(const float4*)(src + 4);
    float* rb = rowbuf + ch*129 + (xq << 3);
    rb[0] = (v0.x-mean)*scale; rb[1] = (v0.y-mean)*scale;
    rb[2] = (v0.z-mean)*scale; rb[3] = (v0.w-mean)*scale;
    rb[4] = (v1.x-mean)*scale; rb[5] = (v1.y-mean)*scale;
    rb[6] = (v1.z-mean)*scale; rb[7] = (v1.w-mean)*scale;
    __syncthreads();
    #pragma unroll
    for (int k = 0; k < 3; ++k){
      int q = t + (k << 9);
      if (q < 1280){
        int p = (q >= 640) ? 1 : 0;
        int qq = q - p*640;
        int col = qq >> 5, cq = qq & 31;
        const float* rbq = rowbuf + cq*129;
        unsigned int d[4];
        #pragma unroll
        for (int e = 0; e < 4; ++e){
          unsigned int lo = f2b(rbq[(8*col + 2*e + p)     & 127]);
          unsigned int hi = f2b(rbq[(8*col + 2*e + 1 + p) & 127]);
          d[e] = lo | (hi << 16);
        }
        uint4v ov = {d[0], d[1], d[2], d[3]};
        *(uint4v*)(pad + (size_t)p*COPYB
                   + ((size_t)(b*148 + r)*20 + col)*512 + cq*16) = ov;
      }
    }
    __syncthreads();
  }
}

// ---------------- Kernel 3: shifted Gram via 32x32x16 MFMA, DMA-staged A ----------------
// 256 blocks = (cg 0..31) x (b 0..7); 512 thr = 8 waves (kq 0..3 y-quarter, ks 0..1 col-half)
// A: parity copy + even residual shift -> per-lane-source global_load_lds into
//    double-buffered LDS; stage(t+1) issued BEFORE compute(t) -> barrier drain ~free.
// B: depth-4 register queue from copy 0.
__global__ __launch_bounds__(512, 1) void k_corr(const unsigned char* __restrict__ pad,
                                                 float* __restrict__ out){
  extern __shared__ char lds[];
  float* sf = (float*)lds;                // epilogue reuse

  int bid = blockIdx.x;
  int b = bid & 7, cg = bid >> 3;
  int dx, d0;
  if (cg < 2){ dx = 0; d0 = cg << 2; }                  // dy groups {0..6}, {4..10}
  else { int q = cg - 2; dx = 1 + q/3; d0 = -10 + 7*(q - 3*(q/3)); }
  int p = dx & 1, dxe = dx - p;           // parity copy + even residual shift

  int tid = threadIdx.x;
  int lane = tid & 63, wvi = tid >> 6;
  int ks = wvi & 1, kq = wvi >> 1;
  unsigned offF = (unsigned)((2*ks + (lane >> 5))*512 + (lane & 31)*16);

  const unsigned char* pb  = pad + (size_t)b*BB;                    // copy 0 (B)
  const unsigned char* pbp = pad + (size_t)p*COPYB + (size_t)b*BB;  // parity copy (A)

  // per-lane DMA source offset: dest (ch=(i&1)*16+(l>>2), dw=l&3) of a chunk
  int tmp = dxe + 2*(lane & 3);
  unsigned phi = (unsigned)(((tmp >> 3) << 9) + ((lane >> 2) << 4) + ((tmp & 6) << 1));

  floatx16 acc[7];
  #pragma unroll
  for (int d = 0; d < 7; ++d) acc[d] = (floatx16)(0.0f);

  auto stageA = [&](int tt, char* dstbuf){
    int rab = 32*(tt >> 2) + 10 + d0;     // pad-row base (0..110)
    int xi4 = (tt & 3) << 2;
    int u0 = wvi * 38;                    // 8 waves x 38 units = 304 = 38 rows x 8 insts
    #pragma unroll
    for (int s = 0; s < 38; ++s){
      int u = u0 + s;
      int r = u >> 3, i = u & 7;
      const unsigned char* g = pbp + (size_t)(rab + r)*ROWB
            + (unsigned)(((xi4 + (i >> 1)) << 9) + ((i & 1) << 8)) + phi;
      gload_lds4(g, dstbuf + (unsigned)u*256);
    }
  };
  auto pBaddr = [&](int tt)->const unsigned char*{
    return pb + ((size_t)((32*(tt >> 2) + 10 + kq*8)*20 + 4*(tt & 3) + 2*ks))*512
              + (unsigned)((lane >> 5)*512 + (lane & 31)*16);
  };

  // prologue: DMA tile 0 into buf0, warm BQ rows 0..3 of tile 0
  stageA(0, lds);
  short8 BQ[4];
  {
    const unsigned char* pB0 = pBaddr(0);
    #pragma unroll
    for (int k = 0; k < 4; ++k) BQ[k] = *(const short8*)(pB0 + (size_t)k*ROWB);
  }
  __syncthreads();                        // drains DMA(0) + BQ warm

  for (int t = 0; t < 16; ++t){
    // issue next tile's DMA first: full compute phase to complete before barrier
    if (t < 15) stageA(t+1, lds + ((t+1)&1)*ABUF);
    // ---- compute tile t: A from LDS buf (t&1), B from register queue ----
    const char* Ab = lds + (t&1)*ABUF + (kq*8)*2048 + offF;
    const unsigned char* pBc = pBaddr(t);
    const unsigned char* pBn = pBaddr(t+1);
    bool more = (t < 15);
    short8 ring[8];
    #pragma unroll
    for (int w = 0; w < 8; ++w) ring[w] = *(const short8*)(Ab + w*2048);
    __builtin_amdgcn_s_setprio(1);
    #pragma unroll
    for (int yl = 0; yl < 8; ++yl){
      short8 bf = BQ[yl & 3];
      #pragma unroll
      for (int d = 0; d < 7; ++d)
        acc[d] = __builtin_amdgcn_mfma_f32_32x32x16_bf16(ring[(yl+d)&7], bf, acc[d], 0, 0, 0);
      if (yl < 4)       BQ[yl & 3] = *(const short8*)(pBc + (size_t)(yl + 4)*ROWB);
      else if (more)    BQ[yl & 3] = *(const short8*)(pBn + (size_t)(yl - 4)*ROWB);
      if (yl < 6) ring[yl & 7] = *(const short8*)(Ab + (yl + 8)*2048);
    }
    __builtin_amdgcn_s_setprio(0);
    __syncthreads();                      // DMA(t+1) + ring reads drained; flip buffers
  }

  // ---- epilogue: 8-wave reduce per dy, triangle-routed stores ----
  int baseb = b * 232848;                 // 528*441
  #pragma unroll
  for (int d = 0; d < 7; ++d){
    #pragma unroll
    for (int r = 0; r < 16; ++r)
      sf[wvi*1024 + r*64 + lane] = acc[d][r];
    __syncthreads();
    int dy = d0 + d;
    #pragma unroll
    for (int k = 0; k < 2; ++k){
      int pp0 = tid + (k << 9);
      float v = 0.f;
      #pragma unroll
      for (int w = 0; w < 8; ++w) v += sf[w*1024 + pp0];
      int reg = pp0 >> 6, ln = pp0 & 63;
      int i = (reg & 3) + 8*(reg >> 2) + 4*(ln >> 5);   // C row (shifted operand channel)
      int j = ln & 31;                                   // C col
      if (i <= j){
        int pp = i*(65 - i)/2 + (j - i);
        out[baseb + pp*441 + (10+dy)*21 + (10+dx)] = v;
        if (i == j && (dy != 0 || dx != 0))
          out[baseb + pp*441 + (10-dy)*21 + (10-dx)] = v;   // autocorr symmetry
      } else {
        int pp = j*(65 - j)/2 + (i - j);
        out[baseb + pp*441 + (10-dy)*21 + (10-dx)] = v;     // pair (j,i) at (-dy,-dx)
      }
    }
    __syncthreads();
  }
}

extern "C" void kernel_launch(void* const* d_in, const int* in_sizes, int n_in,
                              void* d_out, int out_size, void* d_ws, size_t ws_size,
                              hipStream_t stream){
  const float* x = (const float*)d_in[0];
  unsigned char* pad = (unsigned char*)d_ws;             // 2 x 12.12 MB parity copies
  float* stats = (float*)((char*)d_ws + STATS_OFF);      // 256 x {mean, scale}
  float* out = (float*)d_out;
  hipFuncSetAttribute((const void*)k_corr, hipFuncAttributeMaxDynamicSharedMemorySize,
                      LDS_BYTES);
  k_stat<<<dim3(256), dim3(256), 0, stream>>>(x, stats);
  k_pack<<<dim3(296), dim3(512), 0, stream>>>(x, stats, pad);
  k_corr<<<dim3(256), dim3(512), LDS_BYTES, stream>>>(pad, out);
}

// Round 15
// 82.312 us; speedup vs baseline: 1.6899x; 1.6899x over previous
//
#include <hip/hip_runtime.h>
#include <hip/hip_bf16.h>

typedef __attribute__((ext_vector_type(4))) unsigned int uint4v;
typedef __attribute__((ext_vector_type(8))) short short8;
typedef __attribute__((ext_vector_type(4))) float floatx4;

#define NROWP 152
#define ROWB2 12288                      // 4 xi * 32 ch * 96B
#define BB2   ((size_t)NROWP*ROWB2)      // 1,867,776 B per batch per copy
#define COPYB ((size_t)8*BB2)            // 14,942,208 B per parity copy
#define STATS_OFF ((size_t)2*COPYB)      // 29,884,416

__device__ __forceinline__ unsigned short f2b(float f){
  unsigned int u = __float_as_uint(f);
  return (unsigned short)((u + 0x7fffu + ((u >> 16) & 1u)) >> 16);  // RNE
}

// ---------------- Kernel 1: per-(b,c) mean/scale ----------------
__global__ __launch_bounds__(256) void k_stat(const float* __restrict__ x,
                                              float* __restrict__ stats){
  int bid = blockIdx.x;                  // = b*32 + c
  int t = threadIdx.x;
  const float* xc = x + ((size_t)bid << 14);
  float s = 0.f, ss = 0.f;
  #pragma unroll 4
  for (int k = 0; k < 64; ++k){
    float v = xc[t + (k << 8)];
    s += v; ss += v*v;
  }
  #pragma unroll
  for (int m = 32; m >= 1; m >>= 1){
    s  += __shfl_xor(s, m);
    ss += __shfl_xor(ss, m);
  }
  __shared__ float rs[4], rss[4];
  int wv = t >> 6, l = t & 63;
  if (l == 0){ rs[wv] = s; rss[wv] = ss; }
  __syncthreads();
  if (t == 0){
    float S  = rs[0]+rs[1]+rs[2]+rs[3];
    float SS = rss[0]+rss[1]+rss[2]+rss[3];
    float mean = S * (1.f/16384.f);
    float var  = (SS - S*mean) * (1.f/16383.f);   // ddof=1
    float sd = sqrtf(fmaxf(var, 0.f));
    stats[bid*2]   = mean;
    stats[bid*2+1] = (sd < 1e-9f) ? 0.f : 1.f/(sd*128.f);  // 1/(std*sqrt(16384))
  }
}

// ---------------- Kernel 2: standardize + overlapped-window pad ----------------
// pad[p][b][r][xi][ch][96B]: elem e of seg: xs_std[b][ch][(r-10)%128][(32xi+8seg+e+p)%128]
__global__ __launch_bounds__(512) void k_pack(const float* __restrict__ x,
                                              const float* __restrict__ stats,
                                              unsigned char* __restrict__ pad){
  __shared__ float rowbuf[32*129];       // +1 f32 pad per channel row
  int bid = blockIdx.x;
  int b = bid & 7, rg = bid >> 3;        // rg 0..37, rows 4rg..4rg+3
  int t = threadIdx.x;
  int ch = t >> 4, xq = t & 15;
  float mean  = stats[(b*32 + ch)*2];
  float scale = stats[(b*32 + ch)*2 + 1];
  const float* xc = x + ((size_t)(b*32 + ch) << 14);
  for (int rr = 0; rr < 4; ++rr){
    int r = rg*4 + rr;                   // 0..151
    int sy = (r + 118) & 127;            // (r-10) mod 128
    const float* src = xc + (sy << 7) + (xq << 3);
    float4 v0 = *(const float4*)src;
    float4 v1 = *(const float4*)(src + 4);
    float* rb = rowbuf + ch*129 + (xq << 3);
    rb[0] = (v0.x-mean)*scale; rb[1] = (v0.y-mean)*scale;
    rb[2] = (v0.z-mean)*scale; rb[3] = (v0.w-mean)*scale;
    rb[4] = (v1.x-mean)*scale; rb[5] = (v1.y-mean)*scale;
    rb[6] = (v1.z-mean)*scale; rb[7] = (v1.w-mean)*scale;
    __syncthreads();
    #pragma unroll
    for (int k = 0; k < 3; ++k){
      int u = t + (k << 9);              // 0..1535
      int pp = (u >= 768) ? 1 : 0;
      int u2 = u - 768*pp;
      int xi = u2 / 192;
      int u3 = u2 - 192*xi;
      int cq = u3 / 6;
      int seg = u3 - 6*cq;
      const float* rbq = rowbuf + cq*129;
      int x0 = 32*xi + 8*seg + pp;
      unsigned int d[4];
      #pragma unroll
      for (int e = 0; e < 4; ++e){
        unsigned int lo = f2b(rbq[(x0 + 2*e)     & 127]);
        unsigned int hi = f2b(rbq[(x0 + 2*e + 1) & 127]);
        d[e] = lo | (hi << 16);
      }
      uint4v ov = {d[0], d[1], d[2], d[3]};
      *(uint4v*)(pad + (size_t)pp*COPYB + ((size_t)(b*NROWP + r))*ROWB2
                 + (unsigned)(xi*3072 + cq*96 + seg*16)) = ov;
    }
    __syncthreads();
  }
}

// ---------------- Kernel 3: barrier-free streaming Gram via 16x16x32 MFMA ----------------
// 512 blocks = (cg 0..31) x (mh 0..1) x (b 0..7); 512 thr = 8 waves (xs2 x kq2 x nh2)
// Per wave: 2 xi x 64 y-steps; A ring[8] (7x dy reuse) + B BQ[4], all direct global.
__global__ __launch_bounds__(512, 4) void k_corr(const unsigned char* __restrict__ pad,
                                                 float* __restrict__ out){
  __shared__ float sf[3*3584];           // 43008 B: 3 partial slots
  int bid = blockIdx.x;
  int b = bid & 7;
  int r0 = bid >> 3;
  int mh = r0 & 1;
  int cg = r0 >> 1;
  int dx, d0;
  if (cg < 2){ dx = 0; d0 = cg << 2; }                  // dy groups {0..6}, {4..10}
  else { int q = cg - 2; dx = 1 + q/3; d0 = -10 + 7*(q - 3*(q/3)); }
  int p = dx & 1, dxe = dx - p;          // parity copy + even residual shift

  int tid = threadIdx.x;
  int lane = tid & 63, wvi = tid >> 6;
  int nh = wvi & 1, kq = (wvi >> 1) & 1, xs = wvi >> 2;

  const unsigned char* baseA = pad + (size_t)p*COPYB + (size_t)b*BB2;
  const unsigned char* baseB = pad + (size_t)b*BB2;   // copy 0, unshifted
  unsigned oA = (unsigned)((mh*16 + (lane & 15))*96 + 2*dxe + 16*(lane >> 4));
  unsigned oB = (unsigned)((nh*16 + (lane & 15))*96 + 16*(lane >> 4));
  int rowA0 = 10 + kq*64 + d0;           // >= 0 (d0 >= -10)
  int rowB0 = 10 + kq*64;

  floatx4 acc[7];
  #pragma unroll
  for (int d = 0; d < 7; ++d) acc[d] = (floatx4)(0.f);

  #pragma unroll
  for (int xii = 0; xii < 2; ++xii){
    int xi = xs*2 + xii;
    const unsigned char* pA = baseA + (size_t)rowA0*ROWB2 + (unsigned)(xi*3072) + oA;
    const unsigned char* pB = baseB + (size_t)rowB0*ROWB2 + (unsigned)(xi*3072) + oB;
    short8 ring[8], BQ[4];
    #pragma unroll
    for (int w = 0; w < 8; ++w) __builtin_memcpy(&ring[w], pA + (size_t)w*ROWB2, 16);
    #pragma unroll
    for (int k = 0; k < 4; ++k) __builtin_memcpy(&BQ[k], pB + (size_t)k*ROWB2, 16);
    const unsigned char* pAr = pA + (size_t)8*ROWB2;
    const unsigned char* pBr = pB + (size_t)4*ROWB2;
    for (int y8 = 0; y8 < 8; ++y8){      // 8 x 8 = 64 y-steps; inner fully static
      #pragma unroll
      for (int i = 0; i < 8; ++i){
        short8 bf = BQ[i & 3];
        #pragma unroll
        for (int d = 0; d < 7; ++d)
          acc[d] = __builtin_amdgcn_mfma_f32_16x16x32_bf16(ring[(i + d) & 7], bf, acc[d], 0, 0, 0);
        // unconditional refills (rows padded to 152 -> always in bounds)
        __builtin_memcpy(&BQ[i & 3], pBr, 16);  pBr += ROWB2;
        __builtin_memcpy(&ring[i & 7], pAr, 16); pAr += ROWB2;
      }
    }
  }

  // ---- epilogue: reduce (xs,kq) partials, triangle-routed stores ----
  int slot = xs*2 + kq;
  #define RIDX(d,q) ((unsigned)(((((nh*7 + (d)) << 2) + (q)) << 6) + lane))
  if (slot != 0){
    float* dst = sf + (slot - 1)*3584;
    #pragma unroll
    for (int d = 0; d < 7; ++d)
      #pragma unroll
      for (int q = 0; q < 4; ++q) dst[RIDX(d,q)] = acc[d][q];
  }
  __syncthreads();
  if (slot == 0){
    int baseb = b * 232848;              // 528*441
    #pragma unroll
    for (int d = 0; d < 7; ++d){
      int dy = d0 + d;
      #pragma unroll
      for (int q = 0; q < 4; ++q){
        float v = acc[d][q] + sf[RIDX(d,q)] + sf[3584 + RIDX(d,q)] + sf[7168 + RIDX(d,q)];
        int m = ((lane >> 4) << 2) + q;  // C row (M = i, shifted operand)
        int n = lane & 15;               // C col (N = j)
        int i = (mh << 4) + m;
        int j = (nh << 4) + n;
        if (i <= j){
          int pp = i*(65 - i)/2 + (j - i);
          out[baseb + pp*441 + (10+dy)*21 + (10+dx)] = v;
          if (i == j && (dy != 0 || dx != 0))
            out[baseb + pp*441 + (10-dy)*21 + (10-dx)] = v;   // autocorr symmetry
        } else {
          int pp = j*(65 - j)/2 + (i - j);
          out[baseb + pp*441 + (10-dy)*21 + (10-dx)] = v;     // pair (j,i) at (-dy,-dx)
        }
      }
    }
  }
  #undef RIDX
}

extern "C" void kernel_launch(void* const* d_in, const int* in_sizes, int n_in,
                              void* d_out, int out_size, void* d_ws, size_t ws_size,
                              hipStream_t stream){
  const float* x = (const float*)d_in[0];
  unsigned char* pad = (unsigned char*)d_ws;             // 2 x 14.94 MB parity copies
  float* stats = (float*)((char*)d_ws + STATS_OFF);      // 256 x {mean, scale}
  float* out = (float*)d_out;
  k_stat<<<dim3(256), dim3(256), 0, stream>>>(x, stats);
  k_pack<<<dim3(304), dim3(512), 0, stream>>>(x, stats, pad);
  k_corr<<<dim3(512), dim3(512), 0, stream>>>(pad, out);
}